// Round 15
// baseline (626.022 us; speedup 1.0000x reference)
//
#include <hip/hip_runtime.h>
#include <cstdint>

#define TT 16
#define NN 20000
#define CC 128
#define EE 320000
#define KKDIM 384
#define EPSV 1e-5f
#define SBLK 512        // stats stage-A blocks (40 nodes each; >=500 zero pads)
#define PREP_EDGE_BLKS 834   // (EE+383)/384
#define CAST_BLKS 1280

typedef unsigned short u16;
typedef u16 u16x4 __attribute__((ext_vector_type(4)));
typedef u16 u16x8 __attribute__((ext_vector_type(8)));
typedef __bf16 bf16x8 __attribute__((ext_vector_type(8)));
typedef float f32x4 __attribute__((ext_vector_type(4)));

// async 16B global->LDS (linear LDS dest, per-lane global src)
#define GLOAD_LDS16(g_, l_)                                              \
  __builtin_amdgcn_global_load_lds(                                      \
      (const __attribute__((address_space(1))) unsigned int*)(g_),       \
      (__attribute__((address_space(3))) unsigned int*)(l_), 16, 0, 0)

static __device__ __forceinline__ u16 f2bf(float f) {
  union { float f; uint32_t u; } v; v.f = f;
  uint32_t u = v.u;
  return (u16)((u + 0x7FFFu + ((u >> 16) & 1u)) >> 16);
}
static __device__ __forceinline__ float bf2f(u16 h) {
  union { uint32_t u; float f; } v; v.u = ((uint32_t)h) << 16;
  return v.f;
}
// pack two f32 -> two bf16 (RNE) in one VALU op
static __device__ __forceinline__ uint32_t cvtpk(float lo, float hi) {
  uint32_t r;
  asm volatile("v_cvt_pk_bf16_f32 %0, %1, %2" : "=v"(r) : "v"(lo), "v"(hi));
  return r;
}

// ---------------- fused prep: blocks 0..127 weight fold | 128..961 edge count
// | 962.. x f32 -> xb bf16 cast (overlaps cast BW with atomic latency)
__global__ __launch_bounds__(384) void k_prep(const float* __restrict__ Wt,
                                              const float* __restrict__ bt,
                                              const float* __restrict__ Wg,
                                              u16* __restrict__ BmatT,
                                              float* __restrict__ b2,
                                              const int* __restrict__ ei,
                                              const float* __restrict__ ew,
                                              float* __restrict__ deg,
                                              int* __restrict__ cnt,
                                              const float* __restrict__ x,
                                              u16* __restrict__ xb) {
  const int b = blockIdx.x;
  if (b < 128) {
    const int o = b;
    const int kk = threadIdx.x;          // 0..383
    const int k = kk >> 7, i = kk & 127;
    float acc = 0.f;
    for (int c = 0; c < CC; ++c)
      acc += Wg[o * CC + c] * Wt[(size_t)c * 384 + i * 3 + k];
    BmatT[(size_t)o * KKDIM + kk] = f2bf(acc);
    if (kk == 0) {
      float bb = 0.f;
      for (int c = 0; c < CC; ++c) bb += Wg[o * CC + c] * bt[c];
      b2[o] = bb;
    }
  } else if (b < 128 + PREP_EDGE_BLKS) {
    int e = (b - 128) * 384 + threadIdx.x;
    if (e < EE) {
      int d = ei[EE + e];
      atomicAdd(&deg[d], ew[e]);
      atomicAdd(&cnt[d], 1);
    }
  } else {
    const int cb = b - 128 - PREP_EDGE_BLKS;      // 0..CAST_BLKS-1
    const size_t tot = (size_t)TT * NN * CC;      // 40,960,000
    const size_t stride = (size_t)CAST_BLKS * 384 * 8;
    for (size_t i = ((size_t)cb * 384 + threadIdx.x) * 8; i < tot; i += stride) {
      float4 v0 = *(const float4*)(x + i);
      float4 v1 = *(const float4*)(x + i + 4);
      uint32_t p0 = cvtpk(v0.x, v0.y);
      uint32_t p1 = cvtpk(v0.z, v0.w);
      uint32_t p2 = cvtpk(v1.x, v1.y);
      uint32_t p3 = cvtpk(v1.z, v1.w);
      uint32_t* dst = (uint32_t*)(xb + i);
      dst[0] = p0; dst[1] = p1; dst[2] = p2; dst[3] = p3;
    }
  }
}

// ---------------- single-block: dinv (in-place into deg) + exclusive scan
// row length = cnt[n] + 1 (self-loop).
__global__ __launch_bounds__(1024) void k_scan(const int* __restrict__ cnt,
                                               float* __restrict__ deg,
                                               int* __restrict__ rowptr) {
  __shared__ int part[1024];
  const int tid = threadIdx.x;
  const int base = tid * 20;
  int s = 0;
  for (int j = 0; j < 20; ++j) {
    int idx = base + j;
    if (idx < NN) {
      s += cnt[idx] + 1;
      deg[idx] = rsqrtf(deg[idx] + 1.0f);   // deg>=1 always
    }
  }
  part[tid] = s;
  __syncthreads();
  for (int off = 1; off < 1024; off <<= 1) {
    int u = 0;
    if (tid >= off) u = part[tid - off];
    __syncthreads();
    part[tid] += u;
    __syncthreads();
  }
  int run = part[tid] - s;  // exclusive prefix of this chunk
  for (int j = 0; j < 20; ++j) {
    int idx = base + j;
    if (idx < NN) { rowptr[idx] = run; run += cnt[idx] + 1; }
  }
  if (tid == 1023) rowptr[NN] = part[1023];
}

// ---------------- scatter edges + self-loops into packed CSR {col, w}
__global__ __launch_bounds__(256) void k_scatter(const int* __restrict__ ei,
                                                 const float* __restrict__ ew,
                                                 const int* __restrict__ rowptr,
                                                 int* __restrict__ fill,
                                                 const float* __restrict__ dinv,
                                                 int2* __restrict__ cw) {
  int e = blockIdx.x * 256 + threadIdx.x;
  if (e < EE) {
    int s = ei[e], d = ei[EE + e];
    int pos = rowptr[d] + atomicAdd(&fill[d], 1);
    cw[pos] = make_int2(s, __float_as_int(dinv[s] * ew[e] * dinv[d]));
  } else if (e < EE + NN) {
    int n = e - EE;
    float dn = dinv[n];
    int pos = rowptr[n] + atomicAdd(&fill[n], 1);
    cw[pos] = make_int2(n, __float_as_int(dn * dn));
  }
}

// ---------------- fused temporal-conv + GCN-linear GEMM (bf16 MFMA)
// A/B staged via global_load_lds width=16 into UNPADDED [128][64] LDS.
// Bank-conflict fix (rule 21, both-sides): linear LDS dest + inverse-XOR'd
// per-lane GLOBAL source + same XOR on the MFMA ds_read: chunk q ^= row&7.
// Epilogue ht stores are NON-TEMPORAL: ht is only re-read cross-XCD (via L3),
// so keep conv's L2 dedicated to the 3x-tap xb re-reads.
__global__ __launch_bounds__(256) void k_conv(const u16* __restrict__ xb,
                                              const u16* __restrict__ BmatT,
                                              const float* __restrict__ b2,
                                              u16* __restrict__ ht) {
  const int bid = blockIdx.x;
  const int xcd = bid & 7;
  const int s = bid >> 3;              // 0..319
  const int tile = xcd * 20 + (s % 20);
  const int t = s / 20;                // 0..15
  if (tile >= 157) return;
  __shared__ __align__(16) u16 As[8192];   // 128 rows x 64 K (swizzled)
  __shared__ __align__(16) u16 Bs[8192];   // 128 cols x 64 K (swizzled)
  const int row0 = tile * 128;
  const int tid = threadIdx.x;
  const int lane = tid & 63;
  const int wv = tid >> 6;

  f32x4 acc[2][8];
  for (int m = 0; m < 2; ++m)
    for (int nb = 0; nb < 8; ++nb) acc[m][nb] = (f32x4){0.f, 0.f, 0.f, 0.f};

  for (int kt = 0; kt < 6; ++kt) {
    const int kTap = kt >> 1;
    const int i0 = (kt & 1) * 64;
    const int tk = t + kTap - 1;
    const bool tkv = (tk >= 0) && (tk < TT);
    // stage B: 4 x 1KB per wave, inverse-swizzled source
    #pragma unroll
    for (int k = 0; k < 4; ++k) {
      const int Lb = wv * 256 + k * 64;       // wave-uniform chunk base
      const int L = Lb + lane;                // this lane's chunk
      const int col = L >> 3, q = L & 7;
      const u16* src = BmatT + (size_t)col * KKDIM + kt * 64 + ((q ^ (col & 7)) << 3);
      GLOAD_LDS16(src, &Bs[Lb * 8]);
    }
    // stage A
    if (tkv) {
      #pragma unroll
      for (int k = 0; k < 4; ++k) {
        const int Lb = wv * 256 + k * 64;
        const int L = Lb + lane;
        const int r = L >> 3, q = L & 7;
        const int grow = (row0 + r < NN) ? (row0 + r) : (NN - 1);  // clamp; rows>=NN discarded
        const u16* src = xb + ((size_t)tk * NN + grow) * CC + i0 + ((q ^ (r & 7)) << 3);
        GLOAD_LDS16(src, &As[Lb * 8]);
      }
    } else {
      #pragma unroll
      for (int k = 0; k < 4; ++k) {
        const int L = wv * 256 + k * 64 + lane;
        *(u16x8*)&As[L * 8] = (u16x8){0, 0, 0, 0, 0, 0, 0, 0};
      }
    }
    __syncthreads();
    #pragma unroll
    for (int ks = 0; ks < 2; ++ks) {
      const int kq = ks * 4 + (lane >> 4);    // 16B-chunk index in K-half
      const int ar0 = wv * 32 + (lane & 15);
      const int ar1 = ar0 + 16;
      bf16x8 a0 = __builtin_bit_cast(bf16x8,
          *(const u16x8*)&As[ar0 * 64 + ((kq ^ (ar0 & 7)) << 3)]);
      bf16x8 a1 = __builtin_bit_cast(bf16x8,
          *(const u16x8*)&As[ar1 * 64 + ((kq ^ (ar1 & 7)) << 3)]);
      #pragma unroll
      for (int nb = 0; nb < 8; ++nb) {
        const int col = nb * 16 + (lane & 15);
        bf16x8 b = __builtin_bit_cast(bf16x8,
            *(const u16x8*)&Bs[col * 64 + ((kq ^ (col & 7)) << 3)]);
        acc[0][nb] = __builtin_amdgcn_mfma_f32_16x16x32_bf16(a0, b, acc[0][nb], 0, 0, 0);
        acc[1][nb] = __builtin_amdgcn_mfma_f32_16x16x32_bf16(a1, b, acc[1][nb], 0, 0, 0);
      }
    }
    __syncthreads();
  }
  // epilogue: +b2, nt-store bf16 into [n][t][c]
  float b2v[8];
  #pragma unroll
  for (int nb = 0; nb < 8; ++nb) b2v[nb] = b2[nb * 16 + (lane & 15)];
  const int rb = row0 + wv * 32 + ((lane >> 4) << 2);
  #pragma unroll
  for (int m = 0; m < 2; ++m)
    #pragma unroll
    for (int nb = 0; nb < 8; ++nb)
      #pragma unroll
      for (int j = 0; j < 4; ++j) {
        const int r = rb + m * 16 + j;
        if (r < NN) {
          u16 hv = f2bf(acc[m][nb][j] + b2v[nb]);
          __builtin_nontemporal_store(
              hv, ht + (size_t)r * 2048 + t * 128 + nb * 16 + (lane & 15));
        }
      }
}

// ---------------- per-node CSR gather aggregation, XCD t-affinity split
// (round-4 form + nt streams). grid 40000; tgroup = bid&7 (-> XCD);
// block covers 4 nodes (1/wave), each wave gathers 2 t-planes (512B/edge).
// cw loads + agg stores are NON-TEMPORAL so ht is the only L2-resident
// stream (pollution trim: the 2.7MB cw + 5.1MB agg-write-allocate per XCD
// were evicting the 10.25MB ht slice).
__global__ __launch_bounds__(256) void k_agg(const u16* __restrict__ ht,
                                             const int2* __restrict__ cw,
                                             const int* __restrict__ rowptr,
                                             u16* __restrict__ agg) {
  const int bid = blockIdx.x;
  const int tg = bid & 7;
  const int wv = threadIdx.x >> 6, lane = threadIdx.x & 63;
  const int n = (bid >> 3) * 4 + wv;
  const int o0 = tg * 256 + lane * 4;   // elems: planes {2tg, 2tg+1}
  float acc[4] = {0.f, 0.f, 0.f, 0.f};
  const int beg = rowptr[n], end = rowptr[n + 1];
  int p = beg;
  for (; p + 8 <= end; p += 8) {
    const uint64_t* cp = (const uint64_t*)(cw + p);
    uint64_t c0 = __builtin_nontemporal_load(cp);
    uint64_t c1 = __builtin_nontemporal_load(cp + 1);
    uint64_t c2 = __builtin_nontemporal_load(cp + 2);
    uint64_t c3 = __builtin_nontemporal_load(cp + 3);
    uint64_t c4 = __builtin_nontemporal_load(cp + 4);
    uint64_t c5 = __builtin_nontemporal_load(cp + 5);
    uint64_t c6 = __builtin_nontemporal_load(cp + 6);
    uint64_t c7 = __builtin_nontemporal_load(cp + 7);
    u16x4 v0 = *(const u16x4*)(ht + (size_t)(uint32_t)c0 * 2048 + o0);
    u16x4 v1 = *(const u16x4*)(ht + (size_t)(uint32_t)c1 * 2048 + o0);
    u16x4 v2 = *(const u16x4*)(ht + (size_t)(uint32_t)c2 * 2048 + o0);
    u16x4 v3 = *(const u16x4*)(ht + (size_t)(uint32_t)c3 * 2048 + o0);
    u16x4 v4 = *(const u16x4*)(ht + (size_t)(uint32_t)c4 * 2048 + o0);
    u16x4 v5 = *(const u16x4*)(ht + (size_t)(uint32_t)c5 * 2048 + o0);
    u16x4 v6 = *(const u16x4*)(ht + (size_t)(uint32_t)c6 * 2048 + o0);
    u16x4 v7 = *(const u16x4*)(ht + (size_t)(uint32_t)c7 * 2048 + o0);
    #define ACC1(c_, v_)                                              \
      {                                                               \
        const float w_ = __int_as_float((uint32_t)((c_) >> 32));      \
        _Pragma("unroll") for (int k = 0; k < 4; ++k)                 \
            acc[k] = fmaf(bf2f((v_)[k]), w_, acc[k]);                 \
      }
    ACC1(c0, v0) ACC1(c1, v1) ACC1(c2, v2) ACC1(c3, v3)
    ACC1(c4, v4) ACC1(c5, v5) ACC1(c6, v6) ACC1(c7, v7)
  }
  for (; p < end; ++p) {
    uint64_t e = __builtin_nontemporal_load((const uint64_t*)(cw + p));
    u16x4 v = *(const u16x4*)(ht + (size_t)(uint32_t)e * 2048 + o0);
    ACC1(e, v)
  }
  #undef ACC1
  u16x4 sv;
  #pragma unroll
  for (int k = 0; k < 4; ++k) sv[k] = f2bf(acc[k]);
  __builtin_nontemporal_store(sv, (u16x4*)(agg + (size_t)n * 2048 + o0));
}

// ---------------- BN stats stage A: per-block partials, NO atomics.
// grid SBLK blocks x 40 nodes; partial overlays dead ht (after k_agg).
__global__ __launch_bounds__(256) void k_stats(const u16* __restrict__ agg,
                                               float* __restrict__ partial) {
  const int tid = threadIdx.x;
  const int t = tid >> 4, seg = tid & 15;
  const int c0 = seg * 8;
  float s[8], q[8];
  #pragma unroll
  for (int j = 0; j < 8; ++j) { s[j] = 0.f; q[j] = 0.f; }
  const int nbeg = blockIdx.x * 40;
  const int nend = (nbeg + 40 < NN) ? nbeg + 40 : NN;
  for (int n = nbeg; n < nend; ++n) {
    u16x8 v = *(const u16x8*)(agg + (size_t)n * 2048 + t * 128 + c0);
    #pragma unroll
    for (int j = 0; j < 8; ++j) {
      float f = bf2f(v[j]);
      s[j] += f; q[j] += f * f;
    }
  }
  float* dst = partial + (size_t)blockIdx.x * 4096;
  #pragma unroll
  for (int j = 0; j < 8; ++j) {
    dst[t * 256 + c0 + j] = s[j];
    dst[t * 256 + 128 + c0 + j] = q[j];
  }
}

// ---------------- stage B: wave-parallel partial reduce -> scale/shift
__global__ __launch_bounds__(256) void k_fin(const float* __restrict__ partial,
                                             const float* __restrict__ gamma,
                                             const float* __restrict__ beta,
                                             float* __restrict__ scsh) {
  __shared__ float red[256];
  __shared__ float vals[32];
  const int blk = blockIdx.x;
  const int t = blk >> 3;
  const int cbase = (blk & 7) * 16;
  const int tid = threadIdx.x;
  const int tcl = tid & 31;            // 0..15 = su group, 16..31 = sq group
  const int bt = tid >> 5;             // 0..7
  const int tcv = t * 256 + ((tcl < 16) ? (cbase + tcl) : (128 + cbase + tcl - 16));
  float s = 0.f;
  #pragma unroll 8
  for (int k = 0; k < 64; ++k)
    s += partial[(size_t)(bt + (k << 3)) * 4096 + tcv];
  red[tid] = s;
  __syncthreads();
  if (tid < 32) {
    float tot = 0.f;
    #pragma unroll
    for (int i = 0; i < 8; ++i) tot += red[i * 32 + tid];
    vals[tid] = tot;
  }
  __syncthreads();
  if (tid < 16) {
    const int c = cbase + tid;
    float su = vals[tid], sq = vals[16 + tid];
    const float inv_n = 1.f / (float)NN;
    float mu = su * inv_n;
    float var = sq * inv_n - mu * mu;
    float sc = gamma[c] * rsqrtf(var + EPSV);
    scsh[t * 256 + c] = sc;
    scsh[t * 256 + 128 + c] = beta[c] - sc * mu;
  }
}

// ---------------- normalize + ReLU: agg [n][t][c] bf16 -> out [t][n][c] f32
__global__ __launch_bounds__(256) void k_norm(const u16* __restrict__ agg,
                                              const float* __restrict__ scsh,
                                              float* __restrict__ out) {
  const int n = blockIdx.x;
  const int t = threadIdx.x >> 4, seg = threadIdx.x & 15;
  const int c0 = seg * 8;
  u16x8 v = *(const u16x8*)(agg + (size_t)n * 2048 + t * 128 + c0);
  float4 sc0 = *(const float4*)(scsh + t * 256 + c0);
  float4 sc1 = *(const float4*)(scsh + t * 256 + c0 + 4);
  float4 sh0 = *(const float4*)(scsh + t * 256 + 128 + c0);
  float4 sh1 = *(const float4*)(scsh + t * 256 + 128 + c0 + 4);
  f32x4 r0, r1;
  r0[0] = fmaxf(fmaf(bf2f(v[0]), sc0.x, sh0.x), 0.f);
  r0[1] = fmaxf(fmaf(bf2f(v[1]), sc0.y, sh0.y), 0.f);
  r0[2] = fmaxf(fmaf(bf2f(v[2]), sc0.z, sh0.z), 0.f);
  r0[3] = fmaxf(fmaf(bf2f(v[3]), sc0.w, sh0.w), 0.f);
  r1[0] = fmaxf(fmaf(bf2f(v[4]), sc1.x, sh1.x), 0.f);
  r1[1] = fmaxf(fmaf(bf2f(v[5]), sc1.y, sh1.y), 0.f);
  r1[2] = fmaxf(fmaf(bf2f(v[6]), sc1.z, sh1.z), 0.f);
  r1[3] = fmaxf(fmaf(bf2f(v[7]), sc1.w, sh1.w), 0.f);
  float* dst = out + (size_t)t * (NN * CC) + (size_t)n * CC + c0;
  __builtin_nontemporal_store(r0, (f32x4*)dst);
  __builtin_nontemporal_store(r1, (f32x4*)(dst + 4));
}

extern "C" void kernel_launch(void* const* d_in, const int* in_sizes, int n_in,
                              void* d_out, int out_size, void* d_ws, size_t ws_size,
                              hipStream_t stream) {
  const float* x     = (const float*)d_in[0];
  const int*   ei    = (const int*)d_in[1];
  const float* ew    = (const float*)d_in[2];
  const float* Wt    = (const float*)d_in[3];
  const float* bt    = (const float*)d_in[4];
  const float* Wg    = (const float*)d_in[5];
  // d_in[6] = bg: cancels exactly in BatchNorm -> unused
  const float* gamma = (const float*)d_in[7];
  const float* beta  = (const float*)d_in[8];
  float* out = (float*)d_out;
  char* ws = (char*)d_ws;

  // ws layout (bytes)
  const size_t off_cnt    = 0;           // NN*4 = 80000
  const size_t off_fill   = 80000;       // NN*4 = 80000
  const size_t off_deg    = 176384;      // NN*4
  const size_t zero_bytes = 256384;      // cnt|fill|spare|deg zeroed
  const size_t off_rowptr = 256384;      // (NN+1)*4 -> pad
  const size_t off_cw     = 336400;      // (E+N)*8 = 2,720,000
  const size_t off_BmatT  = 3056400;     // 128*384*2 = 98,304
  const size_t off_b2     = 3154704;     // 512
  const size_t off_scsh   = 3155216;     // 16*256*4 = 16,384
  const size_t off_ht     = 3171600;     // N*T*C*2 = 81,920,000
  const size_t off_agg    = 85091600;    // N*T*C*2 = 81,920,000 -> end ~167 MB

  int*   cnt    = (int*)(ws + off_cnt);
  int*   fill   = (int*)(ws + off_fill);
  float* deg    = (float*)(ws + off_deg);
  int*   rowptr = (int*)(ws + off_rowptr);
  int2*  cw     = (int2*)(ws + off_cw);
  u16*   BmatT  = (u16*)(ws + off_BmatT);
  float* b2     = (float*)(ws + off_b2);
  float* scsh   = (float*)(ws + off_scsh);
  u16*   ht     = (u16*)(ws + off_ht);
  u16*   agg    = (u16*)(ws + off_agg);
  u16*   xb     = (u16*)(ws + off_agg);   // xb overlays agg (dead until k_agg)
  float* partial = (float*)(ws + off_ht); // overlays dead ht (after k_agg)

  hipMemsetAsync(ws, 0, zero_bytes, stream);
  k_prep<<<dim3(128 + PREP_EDGE_BLKS + CAST_BLKS), dim3(384), 0, stream>>>(
      Wt, bt, Wg, BmatT, b2, ei, ew, deg, cnt, x, xb);
  k_scan<<<dim3(1), dim3(1024), 0, stream>>>(cnt, deg, rowptr);
  k_scatter<<<dim3((EE + NN + 255) / 256), dim3(256), 0, stream>>>(ei, ew, rowptr,
                                                                   fill, deg, cw);
  k_conv<<<dim3(2560), dim3(256), 0, stream>>>(xb, BmatT, b2, ht);
  k_agg<<<dim3(40000), dim3(256), 0, stream>>>(ht, cw, rowptr, agg);
  k_stats<<<dim3(SBLK), dim3(256), 0, stream>>>(agg, partial);
  k_fin<<<dim3(128), dim3(256), 0, stream>>>(partial, gamma, beta, scsh);
  k_norm<<<dim3(NN), dim3(256), 0, stream>>>(agg, scsh, out);
}

// Round 16
// 456.845 us; speedup vs baseline: 1.3703x; 1.3703x over previous
//
#include <hip/hip_runtime.h>
#include <cstdint>

#define TT 16
#define NN 20000
#define CC 128
#define EE 320000
#define KKDIM 384
#define EPSV 1e-5f
#define SBLK 512        // stats stage-A blocks (40 nodes each; >=500 zero pads)
#define PREP_EDGE_BLKS 834   // (EE+383)/384
#define CAST_BLKS 1280

typedef unsigned short u16;
typedef u16 u16x4 __attribute__((ext_vector_type(4)));
typedef u16 u16x8 __attribute__((ext_vector_type(8)));
typedef __bf16 bf16x8 __attribute__((ext_vector_type(8)));
typedef float f32x4 __attribute__((ext_vector_type(4)));

// async 16B global->LDS (linear LDS dest, per-lane global src)
#define GLOAD_LDS16(g_, l_)                                              \
  __builtin_amdgcn_global_load_lds(                                      \
      (const __attribute__((address_space(1))) unsigned int*)(g_),       \
      (__attribute__((address_space(3))) unsigned int*)(l_), 16, 0, 0)

static __device__ __forceinline__ u16 f2bf(float f) {
  union { float f; uint32_t u; } v; v.f = f;
  uint32_t u = v.u;
  return (u16)((u + 0x7FFFu + ((u >> 16) & 1u)) >> 16);
}
static __device__ __forceinline__ float bf2f(u16 h) {
  union { uint32_t u; float f; } v; v.u = ((uint32_t)h) << 16;
  return v.f;
}
// pack two f32 -> two bf16 (RNE) in one VALU op
static __device__ __forceinline__ uint32_t cvtpk(float lo, float hi) {
  uint32_t r;
  asm volatile("v_cvt_pk_bf16_f32 %0, %1, %2" : "=v"(r) : "v"(lo), "v"(hi));
  return r;
}

// ---------------- fused prep: blocks 0..127 weight fold | 128..961 edge count
// | 962.. x f32 -> xb bf16 cast (overlaps cast BW with atomic latency)
__global__ __launch_bounds__(384) void k_prep(const float* __restrict__ Wt,
                                              const float* __restrict__ bt,
                                              const float* __restrict__ Wg,
                                              u16* __restrict__ BmatT,
                                              float* __restrict__ b2,
                                              const int* __restrict__ ei,
                                              const float* __restrict__ ew,
                                              float* __restrict__ deg,
                                              int* __restrict__ cnt,
                                              const float* __restrict__ x,
                                              u16* __restrict__ xb) {
  const int b = blockIdx.x;
  if (b < 128) {
    const int o = b;
    const int kk = threadIdx.x;          // 0..383
    const int k = kk >> 7, i = kk & 127;
    float acc = 0.f;
    for (int c = 0; c < CC; ++c)
      acc += Wg[o * CC + c] * Wt[(size_t)c * 384 + i * 3 + k];
    BmatT[(size_t)o * KKDIM + kk] = f2bf(acc);
    if (kk == 0) {
      float bb = 0.f;
      for (int c = 0; c < CC; ++c) bb += Wg[o * CC + c] * bt[c];
      b2[o] = bb;
    }
  } else if (b < 128 + PREP_EDGE_BLKS) {
    int e = (b - 128) * 384 + threadIdx.x;
    if (e < EE) {
      int d = ei[EE + e];
      atomicAdd(&deg[d], ew[e]);
      atomicAdd(&cnt[d], 1);
    }
  } else {
    const int cb = b - 128 - PREP_EDGE_BLKS;      // 0..CAST_BLKS-1
    const size_t tot = (size_t)TT * NN * CC;      // 40,960,000
    const size_t stride = (size_t)CAST_BLKS * 384 * 8;
    for (size_t i = ((size_t)cb * 384 + threadIdx.x) * 8; i < tot; i += stride) {
      float4 v0 = *(const float4*)(x + i);
      float4 v1 = *(const float4*)(x + i + 4);
      uint32_t p0 = cvtpk(v0.x, v0.y);
      uint32_t p1 = cvtpk(v0.z, v0.w);
      uint32_t p2 = cvtpk(v1.x, v1.y);
      uint32_t p3 = cvtpk(v1.z, v1.w);
      uint32_t* dst = (uint32_t*)(xb + i);
      dst[0] = p0; dst[1] = p1; dst[2] = p2; dst[3] = p3;
    }
  }
}

// ---------------- single-block: dinv (in-place into deg) + exclusive scan
// row length = cnt[n] + 1 (self-loop).
__global__ __launch_bounds__(1024) void k_scan(const int* __restrict__ cnt,
                                               float* __restrict__ deg,
                                               int* __restrict__ rowptr) {
  __shared__ int part[1024];
  const int tid = threadIdx.x;
  const int base = tid * 20;
  int s = 0;
  for (int j = 0; j < 20; ++j) {
    int idx = base + j;
    if (idx < NN) {
      s += cnt[idx] + 1;
      deg[idx] = rsqrtf(deg[idx] + 1.0f);   // deg>=1 always
    }
  }
  part[tid] = s;
  __syncthreads();
  for (int off = 1; off < 1024; off <<= 1) {
    int u = 0;
    if (tid >= off) u = part[tid - off];
    __syncthreads();
    part[tid] += u;
    __syncthreads();
  }
  int run = part[tid] - s;  // exclusive prefix of this chunk
  for (int j = 0; j < 20; ++j) {
    int idx = base + j;
    if (idx < NN) { rowptr[idx] = run; run += cnt[idx] + 1; }
  }
  if (tid == 1023) rowptr[NN] = part[1023];
}

// ---------------- scatter edges + self-loops into packed CSR {col, w}
__global__ __launch_bounds__(256) void k_scatter(const int* __restrict__ ei,
                                                 const float* __restrict__ ew,
                                                 const int* __restrict__ rowptr,
                                                 int* __restrict__ fill,
                                                 const float* __restrict__ dinv,
                                                 int2* __restrict__ cw) {
  int e = blockIdx.x * 256 + threadIdx.x;
  if (e < EE) {
    int s = ei[e], d = ei[EE + e];
    int pos = rowptr[d] + atomicAdd(&fill[d], 1);
    cw[pos] = make_int2(s, __float_as_int(dinv[s] * ew[e] * dinv[d]));
  } else if (e < EE + NN) {
    int n = e - EE;
    float dn = dinv[n];
    int pos = rowptr[n] + atomicAdd(&fill[n], 1);
    cw[pos] = make_int2(n, __float_as_int(dn * dn));
  }
}

// ---------------- fused temporal-conv + GCN-linear GEMM (bf16 MFMA)
// A/B staged via global_load_lds width=16 into UNPADDED [128][64] LDS.
// Bank-conflict fix (rule 21, both-sides): linear LDS dest + inverse-XOR'd
// per-lane GLOBAL source + same XOR on the MFMA ds_read: chunk q ^= row&7
// (16B chunks, 8/row). Lanes r and r+8 alias -> 2-way = free (m136).
// ht layout: [n][t][c] bf16; grid 2560; bid&7 -> XCD tile affinity.
__global__ __launch_bounds__(256) void k_conv(const u16* __restrict__ xb,
                                              const u16* __restrict__ BmatT,
                                              const float* __restrict__ b2,
                                              u16* __restrict__ ht) {
  const int bid = blockIdx.x;
  const int xcd = bid & 7;
  const int s = bid >> 3;              // 0..319
  const int tile = xcd * 20 + (s % 20);
  const int t = s / 20;                // 0..15
  if (tile >= 157) return;
  __shared__ __align__(16) u16 As[8192];   // 128 rows x 64 K (swizzled)
  __shared__ __align__(16) u16 Bs[8192];   // 128 cols x 64 K (swizzled)
  const int row0 = tile * 128;
  const int tid = threadIdx.x;
  const int lane = tid & 63;
  const int wv = tid >> 6;

  f32x4 acc[2][8];
  for (int m = 0; m < 2; ++m)
    for (int nb = 0; nb < 8; ++nb) acc[m][nb] = (f32x4){0.f, 0.f, 0.f, 0.f};

  for (int kt = 0; kt < 6; ++kt) {
    const int kTap = kt >> 1;
    const int i0 = (kt & 1) * 64;
    const int tk = t + kTap - 1;
    const bool tkv = (tk >= 0) && (tk < TT);
    // stage B: 4 x 1KB per wave, inverse-swizzled source
    #pragma unroll
    for (int k = 0; k < 4; ++k) {
      const int Lb = wv * 256 + k * 64;       // wave-uniform chunk base
      const int L = Lb + lane;                // this lane's chunk
      const int col = L >> 3, q = L & 7;
      const u16* src = BmatT + (size_t)col * KKDIM + kt * 64 + ((q ^ (col & 7)) << 3);
      GLOAD_LDS16(src, &Bs[Lb * 8]);
    }
    // stage A
    if (tkv) {
      #pragma unroll
      for (int k = 0; k < 4; ++k) {
        const int Lb = wv * 256 + k * 64;
        const int L = Lb + lane;
        const int r = L >> 3, q = L & 7;
        const int grow = (row0 + r < NN) ? (row0 + r) : (NN - 1);  // clamp; rows>=NN discarded
        const u16* src = xb + ((size_t)tk * NN + grow) * CC + i0 + ((q ^ (r & 7)) << 3);
        GLOAD_LDS16(src, &As[Lb * 8]);
      }
    } else {
      #pragma unroll
      for (int k = 0; k < 4; ++k) {
        const int L = wv * 256 + k * 64 + lane;
        *(u16x8*)&As[L * 8] = (u16x8){0, 0, 0, 0, 0, 0, 0, 0};
      }
    }
    __syncthreads();
    #pragma unroll
    for (int ks = 0; ks < 2; ++ks) {
      const int kq = ks * 4 + (lane >> 4);    // 16B-chunk index in K-half
      const int ar0 = wv * 32 + (lane & 15);
      const int ar1 = ar0 + 16;
      bf16x8 a0 = __builtin_bit_cast(bf16x8,
          *(const u16x8*)&As[ar0 * 64 + ((kq ^ (ar0 & 7)) << 3)]);
      bf16x8 a1 = __builtin_bit_cast(bf16x8,
          *(const u16x8*)&As[ar1 * 64 + ((kq ^ (ar1 & 7)) << 3)]);
      #pragma unroll
      for (int nb = 0; nb < 8; ++nb) {
        const int col = nb * 16 + (lane & 15);
        bf16x8 b = __builtin_bit_cast(bf16x8,
            *(const u16x8*)&Bs[col * 64 + ((kq ^ (col & 7)) << 3)]);
        acc[0][nb] = __builtin_amdgcn_mfma_f32_16x16x32_bf16(a0, b, acc[0][nb], 0, 0, 0);
        acc[1][nb] = __builtin_amdgcn_mfma_f32_16x16x32_bf16(a1, b, acc[1][nb], 0, 0, 0);
      }
    }
    __syncthreads();
  }
  // epilogue: +b2, store bf16 into [n][t][c]
  float b2v[8];
  #pragma unroll
  for (int nb = 0; nb < 8; ++nb) b2v[nb] = b2[nb * 16 + (lane & 15)];
  const int rb = row0 + wv * 32 + ((lane >> 4) << 2);
  #pragma unroll
  for (int m = 0; m < 2; ++m)
    #pragma unroll
    for (int nb = 0; nb < 8; ++nb)
      #pragma unroll
      for (int j = 0; j < 4; ++j) {
        const int r = rb + m * 16 + j;
        if (r < NN)
          ht[(size_t)r * 2048 + t * 128 + nb * 16 + (lane & 15)] =
              f2bf(acc[m][nb][j] + b2v[nb]);
      }
}

// ---------------- per-node CSR gather aggregation, XCD t-affinity split
// (round-4 form: best measured). grid 40000; tgroup = bid&7 (-> XCD);
// block covers 4 nodes (1/wave), each wave gathers 2 t-planes (512B/edge).
__global__ __launch_bounds__(256) void k_agg(const u16* __restrict__ ht,
                                             const int2* __restrict__ cw,
                                             const int* __restrict__ rowptr,
                                             u16* __restrict__ agg) {
  const int bid = blockIdx.x;
  const int tg = bid & 7;
  const int wv = threadIdx.x >> 6, lane = threadIdx.x & 63;
  const int n = (bid >> 3) * 4 + wv;
  const int o0 = tg * 256 + lane * 4;   // elems: planes {2tg, 2tg+1}
  float acc[4] = {0.f, 0.f, 0.f, 0.f};
  const int beg = rowptr[n], end = rowptr[n + 1];
  int p = beg;
  for (; p + 8 <= end; p += 8) {
    int2 e0 = cw[p],     e1 = cw[p + 1], e2 = cw[p + 2], e3 = cw[p + 3];
    int2 e4 = cw[p + 4], e5 = cw[p + 5], e6 = cw[p + 6], e7 = cw[p + 7];
    u16x4 v0 = *(const u16x4*)(ht + (size_t)e0.x * 2048 + o0);
    u16x4 v1 = *(const u16x4*)(ht + (size_t)e1.x * 2048 + o0);
    u16x4 v2 = *(const u16x4*)(ht + (size_t)e2.x * 2048 + o0);
    u16x4 v3 = *(const u16x4*)(ht + (size_t)e3.x * 2048 + o0);
    u16x4 v4 = *(const u16x4*)(ht + (size_t)e4.x * 2048 + o0);
    u16x4 v5 = *(const u16x4*)(ht + (size_t)e5.x * 2048 + o0);
    u16x4 v6 = *(const u16x4*)(ht + (size_t)e6.x * 2048 + o0);
    u16x4 v7 = *(const u16x4*)(ht + (size_t)e7.x * 2048 + o0);
    #define ACC1(e_, v_)                                              \
      {                                                               \
        const float w_ = __int_as_float((e_).y);                      \
        _Pragma("unroll") for (int k = 0; k < 4; ++k)                 \
            acc[k] = fmaf(bf2f((v_)[k]), w_, acc[k]);                 \
      }
    ACC1(e0, v0) ACC1(e1, v1) ACC1(e2, v2) ACC1(e3, v3)
    ACC1(e4, v4) ACC1(e5, v5) ACC1(e6, v6) ACC1(e7, v7)
  }
  for (; p < end; ++p) {
    int2 e = cw[p];
    u16x4 v = *(const u16x4*)(ht + (size_t)e.x * 2048 + o0);
    ACC1(e, v)
  }
  #undef ACC1
  u16x4 sv;
  #pragma unroll
  for (int k = 0; k < 4; ++k) sv[k] = f2bf(acc[k]);
  *(u16x4*)(agg + (size_t)n * 2048 + o0) = sv;
}

// ---------------- BN stats stage A: per-block partials, NO atomics.
// grid SBLK blocks x 40 nodes; partial overlays dead ht (after k_agg).
__global__ __launch_bounds__(256) void k_stats(const u16* __restrict__ agg,
                                               float* __restrict__ partial) {
  const int tid = threadIdx.x;
  const int t = tid >> 4, seg = tid & 15;
  const int c0 = seg * 8;
  float s[8], q[8];
  #pragma unroll
  for (int j = 0; j < 8; ++j) { s[j] = 0.f; q[j] = 0.f; }
  const int nbeg = blockIdx.x * 40;
  const int nend = (nbeg + 40 < NN) ? nbeg + 40 : NN;
  for (int n = nbeg; n < nend; ++n) {
    u16x8 v = *(const u16x8*)(agg + (size_t)n * 2048 + t * 128 + c0);
    #pragma unroll
    for (int j = 0; j < 8; ++j) {
      float f = bf2f(v[j]);
      s[j] += f; q[j] += f * f;
    }
  }
  float* dst = partial + (size_t)blockIdx.x * 4096;
  #pragma unroll
  for (int j = 0; j < 8; ++j) {
    dst[t * 256 + c0 + j] = s[j];
    dst[t * 256 + 128 + c0 + j] = q[j];
  }
}

// ---------------- stage B: wave-parallel partial reduce -> scale/shift
__global__ __launch_bounds__(256) void k_fin(const float* __restrict__ partial,
                                             const float* __restrict__ gamma,
                                             const float* __restrict__ beta,
                                             float* __restrict__ scsh) {
  __shared__ float red[256];
  __shared__ float vals[32];
  const int blk = blockIdx.x;
  const int t = blk >> 3;
  const int cbase = (blk & 7) * 16;
  const int tid = threadIdx.x;
  const int tcl = tid & 31;            // 0..15 = su group, 16..31 = sq group
  const int bt = tid >> 5;             // 0..7
  const int tcv = t * 256 + ((tcl < 16) ? (cbase + tcl) : (128 + cbase + tcl - 16));
  float s = 0.f;
  #pragma unroll 8
  for (int k = 0; k < 64; ++k)
    s += partial[(size_t)(bt + (k << 3)) * 4096 + tcv];
  red[tid] = s;
  __syncthreads();
  if (tid < 32) {
    float tot = 0.f;
    #pragma unroll
    for (int i = 0; i < 8; ++i) tot += red[i * 32 + tid];
    vals[tid] = tot;
  }
  __syncthreads();
  if (tid < 16) {
    const int c = cbase + tid;
    float su = vals[tid], sq = vals[16 + tid];
    const float inv_n = 1.f / (float)NN;
    float mu = su * inv_n;
    float var = sq * inv_n - mu * mu;
    float sc = gamma[c] * rsqrtf(var + EPSV);
    scsh[t * 256 + c] = sc;
    scsh[t * 256 + 128 + c] = beta[c] - sc * mu;
  }
}

// ---------------- normalize + ReLU: agg [n][t][c] bf16 -> out [t][n][c] f32
__global__ __launch_bounds__(256) void k_norm(const u16* __restrict__ agg,
                                              const float* __restrict__ scsh,
                                              float* __restrict__ out) {
  const int n = blockIdx.x;
  const int t = threadIdx.x >> 4, seg = threadIdx.x & 15;
  const int c0 = seg * 8;
  u16x8 v = *(const u16x8*)(agg + (size_t)n * 2048 + t * 128 + c0);
  float4 sc0 = *(const float4*)(scsh + t * 256 + c0);
  float4 sc1 = *(const float4*)(scsh + t * 256 + c0 + 4);
  float4 sh0 = *(const float4*)(scsh + t * 256 + 128 + c0);
  float4 sh1 = *(const float4*)(scsh + t * 256 + 128 + c0 + 4);
  f32x4 r0, r1;
  r0[0] = fmaxf(fmaf(bf2f(v[0]), sc0.x, sh0.x), 0.f);
  r0[1] = fmaxf(fmaf(bf2f(v[1]), sc0.y, sh0.y), 0.f);
  r0[2] = fmaxf(fmaf(bf2f(v[2]), sc0.z, sh0.z), 0.f);
  r0[3] = fmaxf(fmaf(bf2f(v[3]), sc0.w, sh0.w), 0.f);
  r1[0] = fmaxf(fmaf(bf2f(v[4]), sc1.x, sh1.x), 0.f);
  r1[1] = fmaxf(fmaf(bf2f(v[5]), sc1.y, sh1.y), 0.f);
  r1[2] = fmaxf(fmaf(bf2f(v[6]), sc1.z, sh1.z), 0.f);
  r1[3] = fmaxf(fmaf(bf2f(v[7]), sc1.w, sh1.w), 0.f);
  float* dst = out + (size_t)t * (NN * CC) + (size_t)n * CC + c0;
  __builtin_nontemporal_store(r0, (f32x4*)dst);
  __builtin_nontemporal_store(r1, (f32x4*)(dst + 4));
}

extern "C" void kernel_launch(void* const* d_in, const int* in_sizes, int n_in,
                              void* d_out, int out_size, void* d_ws, size_t ws_size,
                              hipStream_t stream) {
  const float* x     = (const float*)d_in[0];
  const int*   ei    = (const int*)d_in[1];
  const float* ew    = (const float*)d_in[2];
  const float* Wt    = (const float*)d_in[3];
  const float* bt    = (const float*)d_in[4];
  const float* Wg    = (const float*)d_in[5];
  // d_in[6] = bg: cancels exactly in BatchNorm -> unused
  const float* gamma = (const float*)d_in[7];
  const float* beta  = (const float*)d_in[8];
  float* out = (float*)d_out;
  char* ws = (char*)d_ws;

  // ws layout (bytes)
  const size_t off_cnt    = 0;           // NN*4 = 80000
  const size_t off_fill   = 80000;       // NN*4 = 80000
  const size_t off_deg    = 176384;      // NN*4
  const size_t zero_bytes = 256384;      // cnt|fill|spare|deg zeroed
  const size_t off_rowptr = 256384;      // (NN+1)*4 -> pad
  const size_t off_cw     = 336400;      // (E+N)*8 = 2,720,000
  const size_t off_BmatT  = 3056400;     // 128*384*2 = 98,304
  const size_t off_b2     = 3154704;     // 512
  const size_t off_scsh   = 3155216;     // 16*256*4 = 16,384
  const size_t off_ht     = 3171600;     // N*T*C*2 = 81,920,000
  const size_t off_agg    = 85091600;    // N*T*C*2 = 81,920,000 -> end ~167 MB

  int*   cnt    = (int*)(ws + off_cnt);
  int*   fill   = (int*)(ws + off_fill);
  float* deg    = (float*)(ws + off_deg);
  int*   rowptr = (int*)(ws + off_rowptr);
  int2*  cw     = (int2*)(ws + off_cw);
  u16*   BmatT  = (u16*)(ws + off_BmatT);
  float* b2     = (float*)(ws + off_b2);
  float* scsh   = (float*)(ws + off_scsh);
  u16*   ht     = (u16*)(ws + off_ht);
  u16*   agg    = (u16*)(ws + off_agg);
  u16*   xb     = (u16*)(ws + off_agg);   // xb overlays agg (dead until k_agg)
  float* partial = (float*)(ws + off_ht); // overlays dead ht (after k_agg)

  hipMemsetAsync(ws, 0, zero_bytes, stream);
  k_prep<<<dim3(128 + PREP_EDGE_BLKS + CAST_BLKS), dim3(384), 0, stream>>>(
      Wt, bt, Wg, BmatT, b2, ei, ew, deg, cnt, x, xb);
  k_scan<<<dim3(1), dim3(1024), 0, stream>>>(cnt, deg, rowptr);
  k_scatter<<<dim3((EE + NN + 255) / 256), dim3(256), 0, stream>>>(ei, ew, rowptr,
                                                                   fill, deg, cw);
  k_conv<<<dim3(2560), dim3(256), 0, stream>>>(xb, BmatT, b2, ht);
  k_agg<<<dim3(40000), dim3(256), 0, stream>>>(ht, cw, rowptr, agg);
  k_stats<<<dim3(SBLK), dim3(256), 0, stream>>>(agg, partial);
  k_fin<<<dim3(128), dim3(256), 0, stream>>>(partial, gamma, beta, scsh);
  k_norm<<<dim3(NN), dim3(256), 0, stream>>>(agg, scsh, out);
}